// Round 1
// baseline (99.463 us; speedup 1.0000x reference)
//
#include <hip/hip_runtime.h>
#include <hip/hip_bf16.h>

// GlobalAvgPool: x (64, 768, 56, 56) fp32 -> out (64, 768) fp32.
// One block per (b,c) row: 3136 contiguous floats = 784 float4 (16B aligned).
// Memory-bound: 616.6 MB read; target ~6.3 TB/s => ~100 us.

#define ROW_ELEMS   3136      // 56*56
#define ROW_VEC4    784       // 3136/4
#define BLOCK       256
#define INV_ROW     (1.0f / 3136.0f)

__global__ __launch_bounds__(BLOCK) void gap_kernel(const float* __restrict__ x,
                                                    float* __restrict__ out) {
    const int row = blockIdx.x;  // b*768 + c
    const float4* rp = reinterpret_cast<const float4*>(x + (size_t)row * ROW_ELEMS);

    float sum = 0.0f;
    // 784 = 3*256 + 16: threads 0..15 do 4 iters, rest do 3. Fully coalesced.
    for (int i = threadIdx.x; i < ROW_VEC4; i += BLOCK) {
        float4 v = rp[i];
        sum += (v.x + v.y) + (v.z + v.w);
    }

    // Wave-64 butterfly reduce.
    #pragma unroll
    for (int off = 32; off > 0; off >>= 1)
        sum += __shfl_down(sum, off, 64);

    __shared__ float ws[BLOCK / 64];
    const int lane = threadIdx.x & 63;
    const int wid  = threadIdx.x >> 6;
    if (lane == 0) ws[wid] = sum;
    __syncthreads();

    if (threadIdx.x == 0) {
        float t = (ws[0] + ws[1]) + (ws[2] + ws[3]);
        out[row] = t * INV_ROW;
    }
}

extern "C" void kernel_launch(void* const* d_in, const int* in_sizes, int n_in,
                              void* d_out, int out_size, void* d_ws, size_t ws_size,
                              hipStream_t stream) {
    const float* x = (const float*)d_in[0];
    float* out = (float*)d_out;
    const int rows = out_size;  // 64*768 = 49152
    gap_kernel<<<rows, BLOCK, 0, stream>>>(x, out);
}